// Round 3
// baseline (298.405 us; speedup 1.0000x reference)
//
#include <hip/hip_runtime.h>
#include <hip/hip_bf16.h>

#define ALPHA   0.1f
#define S_DECAY 0.95f
#define P_DECAY 0.99f
#define D_EMB   768
#define DK      256

// ---- DPP wave-64 reduction helpers (validated rounds 1-2) ----
template<int ctrl, int row_mask>
__device__ __forceinline__ float dpp_add(float x) {
    int y = __builtin_amdgcn_update_dpp(0, __float_as_int(x), ctrl, row_mask, 0xF, true);
    return x + __int_as_float(y);
}

template<int N>
__device__ __forceinline__ void wave_allred_arr(float (&x)[N]) {
#pragma unroll
    for (int n = 0; n < N; ++n) x[n] = dpp_add<0xB1,  0xF>(x[n]);
#pragma unroll
    for (int n = 0; n < N; ++n) x[n] = dpp_add<0x4E,  0xF>(x[n]);
#pragma unroll
    for (int n = 0; n < N; ++n) x[n] = dpp_add<0x141, 0xF>(x[n]);
#pragma unroll
    for (int n = 0; n < N; ++n) x[n] = dpp_add<0x140, 0xF>(x[n]);
#pragma unroll
    for (int n = 0; n < N; ++n) x[n] = dpp_add<0x142, 0xA>(x[n]);
#pragma unroll
    for (int n = 0; n < N; ++n) x[n] = dpp_add<0x143, 0xC>(x[n]);
#pragma unroll
    for (int n = 0; n < N; ++n)
        x[n] = __int_as_float(__builtin_amdgcn_readlane(__float_as_int(x[n]), 63));
}

__device__ __forceinline__ float dot4v(const float4& a, const float4& b) {
    float t0 = a.x * b.x; t0 = fmaf(a.y, b.y, t0);
    float t1 = a.z * b.z; t1 = fmaf(a.w, b.w, t1);
    return t0 + t1;
}

// ---------------- Kernel 1: K = emb@Wk + bk, V = emb@Wv + bv ----------------
__global__ __launch_bounds__(256) void gemm_kv(
    const float* __restrict__ emb,
    const float* __restrict__ Wk, const float* __restrict__ bk,
    const float* __restrict__ Wv, const float* __restrict__ bv,
    float* __restrict__ K, float* __restrict__ V)
{
    __shared__ float se[4][D_EMB];
    const int j  = threadIdx.x;
    const int r0 = blockIdx.x * 4;

    for (int i = threadIdx.x; i < 4 * D_EMB; i += 256) {
        int r = i / D_EMB, d = i - r * D_EMB;
        se[r][d] = emb[(size_t)(r0 + r) * D_EMB + d];
    }
    __syncthreads();

    float ak0 = 0.f, ak1 = 0.f, ak2 = 0.f, ak3 = 0.f;
    float av0 = 0.f, av1 = 0.f, av2 = 0.f, av3 = 0.f;

    for (int d = 0; d < D_EMB; d += 4) {
#pragma unroll
        for (int dd = 0; dd < 4; ++dd) {
            float wk = Wk[(size_t)(d + dd) * DK + j];
            float wv = Wv[(size_t)(d + dd) * DK + j];
            float e0 = se[0][d + dd], e1 = se[1][d + dd];
            float e2 = se[2][d + dd], e3 = se[3][d + dd];
            ak0 = fmaf(e0, wk, ak0); ak1 = fmaf(e1, wk, ak1);
            ak2 = fmaf(e2, wk, ak2); ak3 = fmaf(e3, wk, ak3);
            av0 = fmaf(e0, wv, av0); av1 = fmaf(e1, wv, av1);
            av2 = fmaf(e2, wv, av2); av3 = fmaf(e3, wv, av3);
        }
    }
    float bkj = bk[j], bvj = bv[j];
    K[(size_t)(r0 + 0) * DK + j] = ak0 + bkj;
    K[(size_t)(r0 + 1) * DK + j] = ak1 + bkj;
    K[(size_t)(r0 + 2) * DK + j] = ak2 + bkj;
    K[(size_t)(r0 + 3) * DK + j] = ak3 + bkj;
    V[(size_t)(r0 + 0) * DK + j] = av0 + bvj;
    V[(size_t)(r0 + 1) * DK + j] = av1 + bvj;
    V[(size_t)(r0 + 2) * DK + j] = av2 + bvj;
    V[(size_t)(r0 + 3) * DK + j] = av3 + bvj;
}

// ------------- Kernel 2: normalize/reverse/pad U arrays, paragraph means, sv -------------
// grid = PADS + PADP blocks of 64 threads.
__global__ __launch_bounds__(64) void norm_means(
    const float* __restrict__ K, const float* __restrict__ V,
    float* __restrict__ USrev, float* __restrict__ PV,
    float* __restrict__ UPrev, float* __restrict__ UPfwd,
    float* __restrict__ SVv, float* __restrict__ biasF,
    int T, int P, int PADS)
{
    const int l = threadIdx.x;
    const int idx = blockIdx.x;
    const float4 z4 = make_float4(0.f, 0.f, 0.f, 0.f);
    if (idx < PADS) {
        int i = idx;                       // process-order index, u_i = kn[T-1-i]
        if (i < T) {
            float4 k4 = reinterpret_cast<const float4*>(K)[(size_t)(T - 1 - i) * 64 + l];
            float ss[1] = { dot4v(k4, k4) };
            wave_allred_arr(ss);
            float inv = 1.0f / fmaxf(sqrtf(ss[0]), 1e-12f);
            reinterpret_cast<float4*>(USrev)[(size_t)i * 64 + l] =
                make_float4(k4.x * inv, k4.y * inv, k4.z * inv, k4.w * inv);
        } else {
            reinterpret_cast<float4*>(USrev)[(size_t)i * 64 + l] = z4;
        }
    } else {
        int p = idx - PADS;
        if (p < P) {
            float4 pk = z4, pv = z4;
#pragma unroll
            for (int s = 0; s < 5; ++s) {
                float4 k4 = reinterpret_cast<const float4*>(K)[(size_t)(p * 5 + s) * 64 + l];
                float4 v4 = reinterpret_cast<const float4*>(V)[(size_t)(p * 5 + s) * 64 + l];
                pk.x += k4.x; pk.y += k4.y; pk.z += k4.z; pk.w += k4.w;
                pv.x += v4.x; pv.y += v4.y; pv.z += v4.z; pv.w += v4.w;
            }
            pk.x *= 0.2f; pk.y *= 0.2f; pk.z *= 0.2f; pk.w *= 0.2f;
            pv.x *= 0.2f; pv.y *= 0.2f; pv.z *= 0.2f; pv.w *= 0.2f;
            reinterpret_cast<float4*>(PV)[(size_t)p * 64 + l] = pv;
            float red[2] = { dot4v(pk, pk), pv.x + pv.y + pv.z + pv.w };
            wave_allred_arr(red);
            if (l == 0) SVv[p] = red[1];
            float inv = 1.0f / fmaxf(sqrtf(red[0]), 1e-12f);
            float4 u = make_float4(pk.x * inv, pk.y * inv, pk.z * inv, pk.w * inv);
            reinterpret_cast<float4*>(UPfwd)[(size_t)p * 64 + l] = u;
            reinterpret_cast<float4*>(UPrev)[(size_t)(P - 1 - p) * 64 + l] = u;
        } else {
            reinterpret_cast<float4*>(PV)[(size_t)p * 64 + l]    = z4;
            reinterpret_cast<float4*>(UPfwd)[(size_t)p * 64 + l] = z4;
            reinterpret_cast<float4*>(UPrev)[(size_t)p * 64 + l] = z4;
            if (l == 0) SVv[p] = 0.f;
            if (p - P < 4) biasF[(p - P) * 64 + l] = 0.f;   // zero bias (atomics target)
        }
    }
}

// ------------- Kernel 3: chunk Gram matrices A = alpha * (scaled strictly-lower Gram) -------------
// grid = (NCS + 2*NCP) * 4 tiles, 256 threads. Type 2 (forward) also accumulates bias via atomics.
__global__ __launch_bounds__(256) void gram_kernel(
    const float* __restrict__ USrev, const float* __restrict__ UPrev,
    const float* __restrict__ UPfwd, const float* __restrict__ SVv,
    float* __restrict__ AS, float* __restrict__ APB, float* __restrict__ APF,
    float* __restrict__ biasF, int NCS, int NCP)
{
    int bid  = blockIdx.x;
    int tile = bid & 3, bc = bid >> 2;
    const float* U; float* A; int m, type;
    if (bc < NCS)            { type = 0; m = bc;              U = USrev; A = AS;  }
    else if (bc < NCS + NCP) { type = 1; m = bc - NCS;        U = UPrev; A = APB; }
    else                     { type = 2; m = bc - NCS - NCP;  U = UPfwd; A = APF; }
    int ti2 = tile >> 1, tj2 = tile & 1;
    int tr = threadIdx.x & 15, tc = threadIdx.x >> 4;
    int i0 = ti2 * 32 + tr * 2, j0 = tj2 * 32 + tc * 2;
    float* Ab = A + (size_t)m * 4096;

    if (ti2 == 0 && tj2 == 1) {   // strictly-upper tile: zeros only
        Ab[(i0    ) * 64 + j0] = 0.f; Ab[(i0    ) * 64 + j0 + 1] = 0.f;
        Ab[(i0 + 1) * 64 + j0] = 0.f; Ab[(i0 + 1) * 64 + j0 + 1] = 0.f;
        return;
    }
    const float4* U4 = reinterpret_cast<const float4*>(U) + (size_t)m * 64 * 64;
    float d00 = 0.f, d01 = 0.f, d10 = 0.f, d11 = 0.f;
    for (int k = 0; k < 64; ++k) {
        float4 r0 = U4[(size_t)(i0    ) * 64 + k];
        float4 r1 = U4[(size_t)(i0 + 1) * 64 + k];
        float4 c0 = U4[(size_t)(j0    ) * 64 + k];
        float4 c1 = U4[(size_t)(j0 + 1) * 64 + k];
        d00 = fmaf(r0.x, c0.x, d00); d00 = fmaf(r0.y, c0.y, d00);
        d00 = fmaf(r0.z, c0.z, d00); d00 = fmaf(r0.w, c0.w, d00);
        d01 = fmaf(r0.x, c1.x, d01); d01 = fmaf(r0.y, c1.y, d01);
        d01 = fmaf(r0.z, c1.z, d01); d01 = fmaf(r0.w, c1.w, d01);
        d10 = fmaf(r1.x, c0.x, d10); d10 = fmaf(r1.y, c0.y, d10);
        d10 = fmaf(r1.z, c0.z, d10); d10 = fmaf(r1.w, c0.w, d10);
        d11 = fmaf(r1.x, c1.x, d11); d11 = fmaf(r1.y, c1.y, d11);
        d11 = fmaf(r1.z, c1.z, d11); d11 = fmaf(r1.w, c1.w, d11);
    }
    // strictly-lower mask + decay scale (type 2); g = pre-alpha scaled Gram
    float g00, g01, g10, g11;
    if (type == 2) {
        g00 = (j0     < i0    ) ? powf(P_DECAY, (float)(i0     - j0    )) * d00 : 0.f;
        g01 = (j0 + 1 < i0    ) ? powf(P_DECAY, (float)(i0     - j0 - 1)) * d01 : 0.f;
        g10 = (j0     < i0 + 1) ? powf(P_DECAY, (float)(i0 + 1 - j0    )) * d10 : 0.f;
        g11 = (j0 + 1 < i0 + 1) ? powf(P_DECAY, (float)(i0 + 1 - j0 - 1)) * d11 : 0.f;
    } else {
        g00 = (j0     < i0    ) ? d00 : 0.f;
        g01 = (j0 + 1 < i0    ) ? d01 : 0.f;
        g10 = (j0     < i0 + 1) ? d10 : 0.f;
        g11 = (j0 + 1 < i0 + 1) ? d11 : 0.f;
    }
    Ab[(i0    ) * 64 + j0]     = ALPHA * g00;
    Ab[(i0    ) * 64 + j0 + 1] = ALPHA * g01;
    Ab[(i0 + 1) * 64 + j0]     = ALPHA * g10;
    Ab[(i0 + 1) * 64 + j0 + 1] = ALPHA * g11;
    if (type == 2) {
        float sv0 = SVv[m * 64 + j0], sv1 = SVv[m * 64 + j0 + 1];
        atomicAdd(&biasF[m * 64 + i0],     g00 * sv0 + g01 * sv1);
        atomicAdd(&biasF[m * 64 + i0 + 1], g10 * sv0 + g11 * sv1);
    }
}

// ------------- Kernel 4: sequential chunk solver (1 block, 4 waves) -------------
__global__ __launch_bounds__(256) void solve_kernel(
    const float* __restrict__ USrev, const float* __restrict__ UPrev,
    const float* __restrict__ UPfwd, const float* __restrict__ SVv,
    const float* __restrict__ AS, const float* __restrict__ APB,
    const float* __restrict__ APF, const float* __restrict__ biasF,
    const float* __restrict__ q,
    float* __restrict__ CS, float* __restrict__ CPB1, float* __restrict__ CPB2,
    float* __restrict__ gscal, int NCS, int NCP)
{
    __shared__ float s_b1[64], s_b2[64], s_c1[64], s_c2[64], s_hh[64];
    __shared__ float4 s_part[4][64], s_part2[4][64];
    __shared__ float s_powd[65];
    const int tid = threadIdx.x, wave = tid >> 6, l = tid & 63;
    if (tid <= 64) s_powd[tid] = powf(P_DECAY, (float)tid);

    // qn
    float4 q4 = reinterpret_cast<const float4*>(q)[l];
    float qs[1] = { dot4v(q4, q4) };
    wave_allred_arr(qs);
    float qinv = 1.0f / fmaxf(sqrtf(qs[0]), 1e-12f);
    float4 qn = make_float4(q4.x * qinv, q4.y * qinv, q4.z * qinv, q4.w * qinv);
    __syncthreads();

    // ================= sentence backward: 16 chunks, single RHS =================
    {
        float4 w1 = qn;
        for (int m = 0; m < NCS; ++m) {
            const float4* Uc = reinterpret_cast<const float4*>(USrev) + (size_t)m * 64 * 64;
            float av[64];
            if (wave == 0) {   // prefetch A row early (hides L2 latency behind phase 1)
                const float4* Ar = reinterpret_cast<const float4*>(AS) + ((size_t)m * 64 + l) * 16;
#pragma unroll
                for (int r = 0; r < 16; ++r) {
                    float4 t = Ar[r];
                    av[4*r] = t.x; av[4*r+1] = t.y; av[4*r+2] = t.z; av[4*r+3] = t.w;
                }
            }
            // phase 1: b = U w
#pragma unroll
            for (int g = 0; g < 4; ++g) {
                int i0 = wave * 16 + g * 4;
                float d[4];
#pragma unroll
                for (int r = 0; r < 4; ++r)
                    d[r] = dot4v(Uc[(size_t)(i0 + r) * 64 + l], w1);
                wave_allred_arr(d);
                if (l == 0) {
                    s_b1[i0] = d[0]; s_b1[i0+1] = d[1]; s_b1[i0+2] = d[2]; s_b1[i0+3] = d[3];
                }
            }
            __syncthreads();
            // phase 2: column-sweep triangular solve (wave 0)
            if (wave == 0) {
                float ct = s_b1[l];
#pragma unroll
                for (int j = 0; j < 64; ++j) {
                    float cj = __int_as_float(__builtin_amdgcn_readlane(__float_as_int(ct), j));
                    ct = fmaf(-cj, av[j], ct);
                }
                s_c1[l] = ct;
                CS[m * 64 + l] = ct;
            }
            __syncthreads();
            // phase 3: w -= alpha * U^T c (split over waves, combine via LDS)
            float4 acc = make_float4(0.f, 0.f, 0.f, 0.f);
#pragma unroll
            for (int r = 0; r < 16; ++r) {
                int i = wave * 16 + r;
                float ci = s_c1[i];
                float4 u = Uc[(size_t)i * 64 + l];
                acc.x = fmaf(ci, u.x, acc.x); acc.y = fmaf(ci, u.y, acc.y);
                acc.z = fmaf(ci, u.z, acc.z); acc.w = fmaf(ci, u.w, acc.w);
            }
            s_part[wave][l] = acc;
            __syncthreads();
            float4 p0 = s_part[0][l], p1 = s_part[1][l], p2 = s_part[2][l], p3 = s_part[3][l];
            w1.x = fmaf(-ALPHA, p0.x + p1.x + p2.x + p3.x, w1.x);
            w1.y = fmaf(-ALPHA, p0.y + p1.y + p2.y + p3.y, w1.y);
            w1.z = fmaf(-ALPHA, p0.z + p1.z + p2.z + p3.z, w1.z);
            w1.w = fmaf(-ALPHA, p0.w + p1.w + p2.w + p3.w, w1.w);
        }
    }

    // ================= paragraph backward: NCP chunks, dual RHS (qn, ones) =================
    {
        float4 w1 = qn;
        float4 w2 = make_float4(1.f, 1.f, 1.f, 1.f);
        for (int m = 0; m < NCP; ++m) {
            const float4* Uc = reinterpret_cast<const float4*>(UPrev) + (size_t)m * 64 * 64;
            float av[64];
            if (wave == 0) {
                const float4* Ar = reinterpret_cast<const float4*>(APB) + ((size_t)m * 64 + l) * 16;
#pragma unroll
                for (int r = 0; r < 16; ++r) {
                    float4 t = Ar[r];
                    av[4*r] = t.x; av[4*r+1] = t.y; av[4*r+2] = t.z; av[4*r+3] = t.w;
                }
            }
#pragma unroll
            for (int g = 0; g < 4; ++g) {
                int i0 = wave * 16 + g * 4;
                float d[8];
#pragma unroll
                for (int r = 0; r < 4; ++r) {
                    float4 u = Uc[(size_t)(i0 + r) * 64 + l];
                    d[r]     = dot4v(u, w1);
                    d[4 + r] = dot4v(u, w2);
                }
                wave_allred_arr(d);
                if (l == 0) {
#pragma unroll
                    for (int r = 0; r < 4; ++r) { s_b1[i0+r] = d[r]; s_b2[i0+r] = d[4+r]; }
                }
            }
            __syncthreads();
            if (wave == 0) {
                float ct1 = s_b1[l], ct2 = s_b2[l];
#pragma unroll
                for (int j = 0; j < 64; ++j) {
                    float c1j = __int_as_float(__builtin_amdgcn_readlane(__float_as_int(ct1), j));
                    float c2j = __int_as_float(__builtin_amdgcn_readlane(__float_as_int(ct2), j));
                    float a = av[j];
                    ct1 = fmaf(-c1j, a, ct1);
                    ct2 = fmaf(-c2j, a, ct2);
                }
                s_c1[l] = ct1; s_c2[l] = ct2;
                CPB1[m * 64 + l] = ct1; CPB2[m * 64 + l] = ct2;
            }
            __syncthreads();
            float4 a1 = make_float4(0.f,0.f,0.f,0.f), a2 = make_float4(0.f,0.f,0.f,0.f);
#pragma unroll
            for (int r = 0; r < 16; ++r) {
                int i = wave * 16 + r;
                float c1 = s_c1[i], c2 = s_c2[i];
                float4 u = Uc[(size_t)i * 64 + l];
                a1.x = fmaf(c1, u.x, a1.x); a1.y = fmaf(c1, u.y, a1.y);
                a1.z = fmaf(c1, u.z, a1.z); a1.w = fmaf(c1, u.w, a1.w);
                a2.x = fmaf(c2, u.x, a2.x); a2.y = fmaf(c2, u.y, a2.y);
                a2.z = fmaf(c2, u.z, a2.z); a2.w = fmaf(c2, u.w, a2.w);
            }
            s_part[wave][l] = a1; s_part2[wave][l] = a2;
            __syncthreads();
            {
                float4 p0 = s_part[0][l], p1 = s_part[1][l], p2 = s_part[2][l], p3 = s_part[3][l];
                w1.x = fmaf(-ALPHA, p0.x+p1.x+p2.x+p3.x, w1.x);
                w1.y = fmaf(-ALPHA, p0.y+p1.y+p2.y+p3.y, w1.y);
                w1.z = fmaf(-ALPHA, p0.z+p1.z+p2.z+p3.z, w1.z);
                w1.w = fmaf(-ALPHA, p0.w+p1.w+p2.w+p3.w, w1.w);
                float4 r0 = s_part2[0][l], r1 = s_part2[1][l], r2 = s_part2[2][l], r3 = s_part2[3][l];
                w2.x = fmaf(-ALPHA, r0.x+r1.x+r2.x+r3.x, w2.x);
                w2.y = fmaf(-ALPHA, r0.y+r1.y+r2.y+r3.y, w2.y);
                w2.z = fmaf(-ALPHA, r0.z+r1.z+r2.z+r3.z, w2.z);
                w2.w = fmaf(-ALPHA, r0.w+r1.w+r2.w+r3.w, w2.w);
            }
        }
    }

    // ================= paragraph forward: NCP chunks, y = M_para . ones =================
    float4 y = make_float4(0.f, 0.f, 0.f, 0.f);
    {
        for (int m = 0; m < NCP; ++m) {
            const float4* Uc = reinterpret_cast<const float4*>(UPfwd) + (size_t)m * 64 * 64;
            float av[64]; float biasl = 0.f, svl = 0.f;
            if (wave == 0) {
                const float4* Ar = reinterpret_cast<const float4*>(APF) + ((size_t)m * 64 + l) * 16;
#pragma unroll
                for (int r = 0; r < 16; ++r) {
                    float4 t = Ar[r];
                    av[4*r] = t.x; av[4*r+1] = t.y; av[4*r+2] = t.z; av[4*r+3] = t.w;
                }
                biasl = biasF[m * 64 + l];
                svl   = SVv[m * 64 + l];
            }
#pragma unroll
            for (int g = 0; g < 4; ++g) {
                int i0 = wave * 16 + g * 4;
                float d[4];
#pragma unroll
                for (int r = 0; r < 4; ++r)
                    d[r] = dot4v(Uc[(size_t)(i0 + r) * 64 + l], y);
                wave_allred_arr(d);
                if (l == 0) {
                    s_b1[i0] = d[0]; s_b1[i0+1] = d[1]; s_b1[i0+2] = d[2]; s_b1[i0+3] = d[3];
                }
            }
            __syncthreads();
            if (wave == 0) {
                // b_i = d^{i+1} (u_i . y) + bias_i
                float ct = fmaf(s_powd[l + 1], s_b1[l], biasl);
#pragma unroll
                for (int j = 0; j < 64; ++j) {
                    float cj = __int_as_float(__builtin_amdgcn_readlane(__float_as_int(ct), j));
                    ct = fmaf(-cj, av[j], ct);
                }
                // h~_i = d^{63-i} (sv_i - alpha c_i)
                s_hh[l] = s_powd[63 - l] * fmaf(-ALPHA, ct, svl);
            }
            __syncthreads();
            float4 acc = make_float4(0.f, 0.f, 0.f, 0.f);
#pragma unroll
            for (int r = 0; r < 16; ++r) {
                int i = wave * 16 + r;
                float hi = s_hh[i];
                float4 u = Uc[(size_t)i * 64 + l];
                acc.x = fmaf(hi, u.x, acc.x); acc.y = fmaf(hi, u.y, acc.y);
                acc.z = fmaf(hi, u.z, acc.z); acc.w = fmaf(hi, u.w, acc.w);
            }
            s_part[wave][l] = acc;
            __syncthreads();
            float4 p0 = s_part[0][l], p1 = s_part[1][l], p2 = s_part[2][l], p3 = s_part[3][l];
            float d64 = s_powd[64];
            y.x = fmaf(d64, y.x, p0.x + p1.x + p2.x + p3.x);
            y.y = fmaf(d64, y.y, p0.y + p1.y + p2.y + p3.y);
            y.z = fmaf(d64, y.z, p0.z + p1.z + p2.z + p3.z);
            y.w = fmaf(d64, y.w, p0.w + p1.w + p2.w + p3.w);
        }
    }
    // doc recall scalar: scal = (qn . y) / max(||y||, 2.56e-10)   (scale-invariant in y)
    float fin[2] = { dot4v(y, y), dot4v(qn, y) };
    wave_allred_arr(fin);
    if (tid == 0) gscal[0] = fin[1] / fmaxf(sqrtf(fin[0]), 2.56e-10f);
}

// ------------- Kernel 5: parallel weighted output accumulation -------------
// block b: sentence chunks [0,NCS), PB1 [NCS,NCS+NCP), PB2 [NCS+NCP,NCS+2NCP)
__global__ __launch_bounds__(256) void accum_kernel(
    const float* __restrict__ V, const float* __restrict__ PV,
    const float* __restrict__ CS, const float* __restrict__ CPB1,
    const float* __restrict__ CPB2,
    float* __restrict__ parts, int T, int P, int NCS, int NCP)
{
    __shared__ float wc[64];
    const int b = blockIdx.x, k = threadIdx.x;
    const float* src; const float* C; int i0, realN; float decay;
    if (b < NCS)            { src = V;  C = CS;   i0 = b * 64;              realN = T; decay = S_DECAY; }
    else if (b < NCS + NCP) { src = PV; C = CPB1; i0 = (b - NCS) * 64;       realN = P; decay = P_DECAY; }
    else                    { src = PV; C = CPB2; i0 = (b - NCS - NCP) * 64; realN = P; decay = P_DECAY; }
    if (k < 64) wc[k] = powf(decay, (float)(i0 + k)) * C[i0 + k];
    __syncthreads();
    float acc = 0.f;
    for (int ii = 0; ii < 64; ++ii) {
        int i = i0 + ii;
        if (i < realN)
            acc = fmaf(wc[ii], src[(size_t)(realN - 1 - i) * DK + k], acc);
    }
    parts[(size_t)b * DK + k] = acc;
}

// ------------- Kernel 6: final combine -------------
__global__ __launch_bounds__(256) void combine_kernel(
    const float* __restrict__ parts, const float* __restrict__ gscal,
    float* __restrict__ out, int NCS, int NCP)
{
    const int k = threadIdx.x;
    float ss = 0.f, sp = 0.f, sd = 0.f;
    for (int b = 0; b < NCS; ++b)               ss += parts[(size_t)b * DK + k];
    for (int b = NCS; b < NCS + NCP; ++b)       sp += parts[(size_t)b * DK + k];
    for (int b = NCS + NCP; b < NCS + 2*NCP; ++b) sd += parts[(size_t)b * DK + k];
    out[k] = 0.2f * ss + 0.3f * sp + (0.5f / 256.0f) * gscal[0] * sd;
}

extern "C" void kernel_launch(void* const* d_in, const int* in_sizes, int n_in,
                              void* d_out, int out_size, void* d_ws, size_t ws_size,
                              hipStream_t stream) {
    const float* emb = (const float*)d_in[0];
    const float* q   = (const float*)d_in[1];
    const float* Wk  = (const float*)d_in[2];
    const float* bk  = (const float*)d_in[3];
    const float* Wv  = (const float*)d_in[4];
    const float* bv  = (const float*)d_in[5];

    const int T = in_sizes[0] / D_EMB;        // 1000
    const int P = T / 5;                      // 200
    const int NCS  = (T + 63) / 64;           // 16
    const int NCP  = (P + 63) / 64;           // 4
    const int PADS = NCS * 64;                // 1024
    const int PADP = NCP * 64;                // 256

    float* ws    = (float*)d_ws;
    float* K     = ws;                               // T*256
    float* V     = K     + (size_t)T * DK;           // T*256
    float* USrev = V     + (size_t)T * DK;           // PADS*256
    float* PV    = USrev + (size_t)PADS * DK;        // PADP*256
    float* UPrev = PV    + (size_t)PADP * DK;        // PADP*256
    float* UPfwd = UPrev + (size_t)PADP * DK;        // PADP*256
    float* SVv   = UPfwd + (size_t)PADP * DK;        // PADP
    float* AS    = SVv   + PADP;                     // NCS*4096
    float* APB   = AS    + (size_t)NCS * 4096;       // NCP*4096
    float* APF   = APB   + (size_t)NCP * 4096;       // NCP*4096
    float* biasF = APF   + (size_t)NCP * 4096;       // PADP
    float* CS    = biasF + PADP;                     // PADS
    float* CPB1  = CS    + PADS;                     // PADP
    float* CPB2  = CPB1  + PADP;                     // PADP
    float* gscal = CPB2  + PADP;                     // 4
    float* parts = gscal + 4;                        // (NCS+2*NCP)*256

    gemm_kv<<<T / 4, 256, 0, stream>>>(emb, Wk, bk, Wv, bv, K, V);
    norm_means<<<PADS + PADP, 64, 0, stream>>>(K, V, USrev, PV, UPrev, UPfwd, SVv, biasF, T, P, PADS);
    gram_kernel<<<(NCS + 2 * NCP) * 4, 256, 0, stream>>>(USrev, UPrev, UPfwd, SVv, AS, APB, APF, biasF, NCS, NCP);
    solve_kernel<<<1, 256, 0, stream>>>(USrev, UPrev, UPfwd, SVv, AS, APB, APF, biasF, q,
                                        CS, CPB1, CPB2, gscal, NCS, NCP);
    accum_kernel<<<NCS + 2 * NCP, 256, 0, stream>>>(V, PV, CS, CPB1, CPB2, parts, T, P, NCS, NCP);
    combine_kernel<<<1, 256, 0, stream>>>(parts, gscal, (float*)d_out, NCS, NCP);
}